// Round 1
// baseline (106.162 us; speedup 1.0000x reference)
//
#include <hip/hip_runtime.h>

#define HH 512
#define WW 512

// med3(a,b,c) = max(min(a,b), min(max(a,b), c))  -> v_med3_f32
__device__ __forceinline__ float med3f(float a, float b, float c) {
    return fmaxf(fminf(a, b), fminf(fmaxf(a, b), c));
}
__device__ __forceinline__ float min3f(float a, float b, float c) {
    return fminf(fminf(a, b), c);
}
__device__ __forceinline__ float max3f(float a, float b, float c) {
    return fmaxf(fmaxf(a, b), c);
}

__global__ __launch_bounds__(256) void median3x3_kernel(
    const float* __restrict__ in, float* __restrict__ out) {
    // Each thread produces 4 consecutive output pixels in one row.
    const int quads_per_row = WW / 4;                 // 128
    int gid    = blockIdx.x * 256 + threadIdx.x;      // total = NIMG*H*W/4
    int row_id = gid >> 7;                            // / quads_per_row
    int q      = gid & (quads_per_row - 1);
    int img    = row_id >> 9;                         // / HH
    int y      = row_id & (HH - 1);
    int x0     = q << 2;

    const float* base = in + (size_t)img * HH * WW;
    int ym1 = (y == 0)      ? 1      : y - 1;
    int yp1 = (y == HH - 1) ? HH - 2 : y + 1;

    float c0[6], c1[6], c2[6];
    {
        const float* rp = base + (size_t)ym1 * WW;
        float4 m = *(const float4*)(rp + x0);
        c0[0] = (x0 == 0) ? rp[1] : rp[x0 - 1];
        c0[1] = m.x; c0[2] = m.y; c0[3] = m.z; c0[4] = m.w;
        c0[5] = (x0 + 4 >= WW) ? rp[WW - 2] : rp[x0 + 4];
    }
    {
        const float* rp = base + (size_t)y * WW;
        float4 m = *(const float4*)(rp + x0);
        c1[0] = (x0 == 0) ? rp[1] : rp[x0 - 1];
        c1[1] = m.x; c1[2] = m.y; c1[3] = m.z; c1[4] = m.w;
        c1[5] = (x0 + 4 >= WW) ? rp[WW - 2] : rp[x0 + 4];
    }
    {
        const float* rp = base + (size_t)yp1 * WW;
        float4 m = *(const float4*)(rp + x0);
        c2[0] = (x0 == 0) ? rp[1] : rp[x0 - 1];
        c2[1] = m.x; c2[2] = m.y; c2[3] = m.z; c2[4] = m.w;
        c2[5] = (x0 + 4 >= WW) ? rp[WW - 2] : rp[x0 + 4];
    }

    // Per-column vertical sort3 (lo/md/hi), 6 columns.
    float lo[6], md[6], hi[6];
#pragma unroll
    for (int j = 0; j < 6; ++j) {
        float a = c0[j], b = c1[j], d = c2[j];
        lo[j] = min3f(a, b, d);
        md[j] = med3f(a, b, d);
        hi[j] = max3f(a, b, d);
    }

    // median9 = med3( max3(lo), med3(md), min3(hi) )  [exact identity]
    float res[4];
#pragma unroll
    for (int k = 0; k < 4; ++k) {
        float A = max3f(lo[k], lo[k + 1], lo[k + 2]);
        float B = med3f(md[k], md[k + 1], md[k + 2]);
        float C = min3f(hi[k], hi[k + 1], hi[k + 2]);
        res[k] = med3f(A, B, C);
    }

    float4 o;
    o.x = res[0]; o.y = res[1]; o.z = res[2]; o.w = res[3];
    *(float4*)(out + (size_t)img * HH * WW + (size_t)y * WW + x0) = o;
}

extern "C" void kernel_launch(void* const* d_in, const int* in_sizes, int n_in,
                              void* d_out, int out_size, void* d_ws, size_t ws_size,
                              hipStream_t stream) {
    const float* in = (const float*)d_in[0];
    float* out = (float*)d_out;
    int total   = in_sizes[0];        // 16*3*512*512 = 12,582,912
    int threads = total >> 2;         // 4 px per thread
    int blocks  = threads / 256;      // 12288, exact
    median3x3_kernel<<<blocks, 256, 0, stream>>>(in, out);
}

// Round 3
// 102.169 us; speedup vs baseline: 1.0391x; 1.0391x over previous
//
#include <hip/hip_runtime.h>

#define HH 512
#define WW 512
#define RPT 8   // output rows per thread

typedef float f32x4 __attribute__((ext_vector_type(4)));

// med3(a,b,c) -> v_med3_f32 ; min3/max3 -> v_min3_f32 / v_max3_f32
__device__ __forceinline__ float med3f(float a, float b, float c) {
    return fmaxf(fminf(a, b), fminf(fmaxf(a, b), c));
}
__device__ __forceinline__ float min3f(float a, float b, float c) {
    return fminf(fminf(a, b), c);
}
__device__ __forceinline__ float max3f(float a, float b, float c) {
    return fmaxf(fmaxf(a, b), c);
}

// One wave covers a full 512-px row: lane L owns columns L*8 .. L*8+7.
// Row holds the 10 columns x0-1 .. x0+8 needed for an 8-px-wide median row.
struct Row { float v[10]; };

__device__ __forceinline__ Row load_row(const float* __restrict__ rp, int x0, int lane) {
    f32x4 a = *(const f32x4*)(rp + x0);
    f32x4 b = *(const f32x4*)(rp + x0 + 4);
    Row d;
    d.v[1] = a.x; d.v[2] = a.y; d.v[3] = a.z; d.v[4] = a.w;
    d.v[5] = b.x; d.v[6] = b.y; d.v[7] = b.z; d.v[8] = b.w;
    // halo from neighbor lanes; image edges reflect into own registers
    float lf = __shfl_up(b.w, 1);   // col x0-1 = left lane's b.w
    float rt = __shfl_down(a.x, 1); // col x0+8 = right lane's a.x
    d.v[0] = (lane == 0)  ? a.y : lf;   // reflect: col -1  -> col 1
    d.v[9] = (lane == 63) ? b.z : rt;   // reflect: col 512 -> col 510
    return d;
}

__global__ __launch_bounds__(256) void median3x3_kernel(
    const float* __restrict__ in, float* __restrict__ out) {
    const int lane = threadIdx.x & 63;
    const int wv   = threadIdx.x >> 6;          // 0..3
    const int tile = blockIdx.x * 4 + wv;       // row-group id (8 rows each)
    const int img  = tile >> 6;                 // HH/RPT = 64 groups per plane
    const int y0   = (tile & 63) * RPT;
    const int x0   = lane << 3;

    const float* base  = in  + (size_t)img * (HH * WW);
    float*       obase = out + (size_t)img * (HH * WW);

    // rolling 4-row register window, distance-2 prefetch
    Row rows[4];
    rows[0] = load_row(base + (size_t)((y0 == 0) ? 1 : y0 - 1) * WW, x0, lane);
    rows[1] = load_row(base + (size_t)y0 * WW, x0, lane);
    rows[2] = load_row(base + (size_t)(y0 + 1) * WW, x0, lane);  // y0+1 <= 505, in range

#pragma unroll
    for (int r = 0; r < RPT; ++r) {
        if (r < RPT - 1) {                       // prefetch row y0+r+2
            int yn = y0 + r + 2;
            if (yn >= HH) yn = HH - 2;           // reflect: row 512 -> 510
            rows[(r + 3) & 3] = load_row(base + (size_t)yn * WW, x0, lane);
        }
        const Row& p = rows[r & 3];              // row y0+r-1
        const Row& c = rows[(r + 1) & 3];        // row y0+r
        const Row& n = rows[(r + 2) & 3];        // row y0+r+1

        float lo[10], md[10], hi[10];
#pragma unroll
        for (int j = 0; j < 10; ++j) {
            lo[j] = min3f(p.v[j], c.v[j], n.v[j]);
            md[j] = med3f(p.v[j], c.v[j], n.v[j]);
            hi[j] = max3f(p.v[j], c.v[j], n.v[j]);
        }
        float res[8];
#pragma unroll
        for (int k = 0; k < 8; ++k) {
            res[k] = med3f(max3f(lo[k], lo[k + 1], lo[k + 2]),
                           med3f(md[k], md[k + 1], md[k + 2]),
                           min3f(hi[k], hi[k + 1], hi[k + 2]));
        }
        float* op = obase + (size_t)(y0 + r) * WW + x0;
        f32x4 o0 = {res[0], res[1], res[2], res[3]};
        f32x4 o1 = {res[4], res[5], res[6], res[7]};
        __builtin_nontemporal_store(o0, (f32x4*)op);
        __builtin_nontemporal_store(o1, (f32x4*)(op + 4));
    }
}

extern "C" void kernel_launch(void* const* d_in, const int* in_sizes, int n_in,
                              void* d_out, int out_size, void* d_ws, size_t ws_size,
                              hipStream_t stream) {
    const float* in = (const float*)d_in[0];
    float* out = (float*)d_out;
    int planes = in_sizes[0] / (HH * WW);        // 16*3 = 48
    int blocks = planes * (HH / RPT) / 4;        // 48*64/4 = 768
    median3x3_kernel<<<blocks, 256, 0, stream>>>(in, out);
}